// Round 2
// baseline (174295.459 us; speedup 1.0000x reference)
//
#include <hip/hip_runtime.h>
#include <stdint.h>
#include <math.h>

// Persistent barrier-free 2-layer LSTM rollout, MI355X (gfx950).
// 512 WGs x 128 thr; wave (wg,wv) owns h-unit je=2*wg+wv of both layers.
// Critical chain per step: poll h0 -> 4 gate rows -> publish h1 ->
//                          poll h1 -> W2 row -> cell0 -> publish h0.
// Whh0/Whh1 rows + threefry RNG run post-publish (shadow time).
// h exchanged as 8B {f32 value | u32 step-tag} relaxed agent atomics.
// No __syncthreads in the main loop; waves fully decoupled.

#define H     1024
#define NSTEP 8192
#define NWG   512
#define BLK   128
#define NROW  13   // 0-3 Wih1 gates, 4-7 Whh0 gates, 8-11 Whh1 gates, 12 W2

typedef _Float16 h2 __attribute__((ext_vector_type(2)));
typedef _Float16 h8 __attribute__((ext_vector_type(8)));

__device__ __forceinline__ unsigned long long pack_vt(float v, uint32_t tag){
  return ((unsigned long long)tag << 32) | (unsigned long long)__float_as_uint(v);
}

// Exact JAX threefry2x32.
__device__ __forceinline__ uint2 tf2x32(uint32_t k0, uint32_t k1, uint32_t x0, uint32_t x1){
  uint32_t k2 = k0 ^ k1 ^ 0x1BD11BDAu;
  x0 += k0; x1 += k1;
#define TFR(r) { x0 += x1; x1 = (x1 << (r)) | (x1 >> (32 - (r))); x1 ^= x0; }
  TFR(13) TFR(15) TFR(26) TFR(6)
  x0 += k1; x1 += k2 + 1u;
  TFR(17) TFR(29) TFR(16) TFR(24)
  x0 += k2; x1 += k0 + 2u;
  TFR(13) TFR(15) TFR(26) TFR(6)
  x0 += k0; x1 += k1 + 3u;
  TFR(17) TFR(29) TFR(16) TFR(24)
  x0 += k1; x1 += k2 + 4u;
  TFR(13) TFR(15) TFR(26) TFR(6)
  x0 += k2; x1 += k0 + 5u;
#undef TFR
  uint2 r; r.x = x0; r.y = x1; return r;
}

// keys = threefry_split(key(42), 8192)
__device__ __forceinline__ uint32_t jax_word(uint32_t i){
  return (i < 8192u) ? tf2x32(0u, 42u, i, i + 8192u).x
                     : tf2x32(0u, 42u, i - 8192u, i).y;
}

__device__ __forceinline__ float wred64(float x){
  #pragma unroll
  for(int off = 32; off > 0; off >>= 1) x += __shfl_xor(x, off, 64);
  return x;
}

#if __has_builtin(__builtin_amdgcn_fdot2)
__device__ __forceinline__ float fdot2f(h2 a, h2 b, float c){ return __builtin_amdgcn_fdot2(a, b, c, false); }
#else
__device__ __forceinline__ float fdot2f(h2 a, h2 b, float c){
  return (float)a.x * (float)b.x + (float)a.y * (float)b.y + c;
}
#endif

__device__ __forceinline__ float sigm(float x){
  x = fminf(fmaxf(x, -30.f), 30.f);
  return 1.f / (1.f + __expf(-x));
}
__device__ __forceinline__ float tanh_f(float x){
  x = fminf(fmaxf(x, -15.f), 15.f);
  float e = __expf(2.f * x);
  return (e - 1.f) / (e + 1.f);
}

// Poll 16 slots (this lane's h fragment) straight into registers; no LDS.
__device__ __forceinline__ void poll_h(const unsigned long long* __restrict__ buf,
                                       uint32_t tag, int lane, h2* hv){
  const unsigned long long* p0 = buf + (lane << 3);        // slots 8l..8l+7
  const unsigned long long* p1 = buf + 512 + (lane << 3);  // slots 512+8l..
  unsigned long long pv[16];
  for(;;){
    #pragma unroll
    for(int k = 0; k < 8; k++)
      pv[k] = __hip_atomic_load((unsigned long long*)(p0 + k), __ATOMIC_RELAXED, __HIP_MEMORY_SCOPE_AGENT);
    #pragma unroll
    for(int k = 0; k < 8; k++)
      pv[8+k] = __hip_atomic_load((unsigned long long*)(p1 + k), __ATOMIC_RELAXED, __HIP_MEMORY_SCOPE_AGENT);
    uint32_t bad = 0;
    #pragma unroll
    for(int k = 0; k < 16; k++) bad |= ((uint32_t)(pv[k] >> 32)) ^ tag;
    if(!bad) break;
    __builtin_amdgcn_s_sleep(1);
  }
  #pragma unroll
  for(int j = 0; j < 4; j++){
    h2 a; a.x = (_Float16)__uint_as_float((uint32_t)pv[2*j]);
          a.y = (_Float16)__uint_as_float((uint32_t)pv[2*j+1]);
    hv[j] = a;
    h2 b; b.x = (_Float16)__uint_as_float((uint32_t)pv[8+2*j]);
          b.y = (_Float16)__uint_as_float((uint32_t)pv[8+2*j+1]);
    hv[4+j] = b;
  }
}

// One row dot partial: lane l covers h2 [4l,4l+4) and [256+4l,256+4l+4).
// Both are 16B-aligned b128 LDS reads, lane stride 16B -> conflict-free.
__device__ __forceinline__ float row_part(const h2* __restrict__ wrow, int lane, const h2* hv){
  h8 wl = *(const h8*)(wrow + (lane << 2));
  h8 wh = *(const h8*)(wrow + 256 + (lane << 2));
  float a0 = 0.f, a1 = 0.f;
  h2 w;
  w = __builtin_shufflevector(wl, wl, 0, 1); a0 = fdot2f(w, hv[0], a0);
  w = __builtin_shufflevector(wl, wl, 2, 3); a1 = fdot2f(w, hv[1], a1);
  w = __builtin_shufflevector(wl, wl, 4, 5); a0 = fdot2f(w, hv[2], a0);
  w = __builtin_shufflevector(wl, wl, 6, 7); a1 = fdot2f(w, hv[3], a1);
  w = __builtin_shufflevector(wh, wh, 0, 1); a0 = fdot2f(w, hv[4], a0);
  w = __builtin_shufflevector(wh, wh, 2, 3); a1 = fdot2f(w, hv[5], a1);
  w = __builtin_shufflevector(wh, wh, 4, 5); a0 = fdot2f(w, hv[6], a0);
  w = __builtin_shufflevector(wh, wh, 6, 7); a1 = fdot2f(w, hv[7], a1);
  return a0 + a1;
}

__global__ void __launch_bounds__(BLK)
lstm_persist(const float* __restrict__ ctx,  const float* __restrict__ W1p,  const float* __restrict__ b1p,
             const float* __restrict__ Wih0, const float* __restrict__ Whh0,
             const float* __restrict__ bih0, const float* __restrict__ bhh0,
             const float* __restrict__ Wih1, const float* __restrict__ Whh1,
             const float* __restrict__ bih1, const float* __restrict__ bhh1,
             const float* __restrict__ W2p,  const float* __restrict__ b2p,
             float* __restrict__ out,
             unsigned long long* __restrict__ h0buf,
             unsigned long long* __restrict__ h1buf)
{
  __shared__ h2 wts[2][NROW][H/2];   // 52 KB -> 2 WGs/CU (104 KB), 4 waves/CU

  const int tid  = threadIdx.x;
  const int wg   = blockIdx.x;
  const int wv   = tid >> 6;
  const int lane = tid & 63;
  const int je   = (wg << 1) + wv;

  h2 (*w)[H/2] = wts[wv];

  // ---- one-time: stage this wave's 13 rows as f16 (coalesced float2 reads)
  #pragma unroll 1
  for(int r = 0; r < NROW; r++){
    const float* rowp;
    if     (r < 4)  rowp = Wih1 + (size_t)(r*H + je) * H;
    else if(r < 8)  rowp = Whh0 + (size_t)((r-4)*H + je) * H;
    else if(r < 12) rowp = Whh1 + (size_t)((r-8)*H + je) * H;
    else            rowp = W2p;
    const float2* s2 = (const float2*)rowp;
    for(int c = lane; c < H/2; c += 64){
      float2 f = s2[c]; h2 p; p.x = (_Float16)f.x; p.y = (_Float16)f.y; w[r][c] = p;
    }
  }

  // per-wave scalars
  float b0g[4], b1g[4], w0g[4];
  #pragma unroll
  for(int g = 0; g < 4; g++){
    b0g[g] = bih0[g*H + je] + bhh0[g*H + je];
    b1g[g] = bih1[g*H + je] + bhh1[g*H + je];
    w0g[g] = Wih0[g*H + je];
  }
  const float b2v = b2p[0];

  // x0 = W1 @ context + b1
  float xacc = 0.f;
  for(int c = lane; c < 512; c += 64) xacc += W1p[c] * ctx[c];
  const float x0 = wred64(xacc) + b1p[0];

  float c0, c1 = 0.f, logp = 0.f;
  float a0[4];
  float a1[4] = {0.f, 0.f, 0.f, 0.f};

  // h0(0) from x0
  {
    float gi = sigm (w0g[0]*x0 + b0g[0]);
    float gf = sigm (w0g[1]*x0 + b0g[1]);
    float gg = tanh_f(w0g[2]*x0 + b0g[2]);
    float go = sigm (w0g[3]*x0 + b0g[3]);
    c0 = gi * gg;
    float h0v = go * tanh_f(c0);
    if(lane == 0)
      __hip_atomic_store(&h0buf[je], pack_vt(h0v, 1u), __ATOMIC_RELAXED, __HIP_MEMORY_SCOPE_AGENT);
  }

  h2 hv[8];
  float u = 0.f;   // uniform for current step, produced in P1 shadow

  #pragma unroll 1
  for(int t = 0; t < NSTEP; t++){
    const uint32_t tt = (uint32_t)t;

    // ================= P1: consume h0(t) =================
    poll_h(h0buf, tt + 1u, lane, hv);

    // critical: 4 layer-1 gate rows (Wih1) only
    float s1[4];
    #pragma unroll
    for(int r = 0; r < 4; r++) s1[r] = row_part(&w[r][0], lane, hv);
    #pragma unroll
    for(int off = 32; off > 0; off >>= 1){
      #pragma unroll
      for(int r = 0; r < 4; r++) s1[r] += __shfl_xor(s1[r], off, 64);
    }
    {
      float gi = sigm (s1[0] + a1[0] + b1g[0]);
      float gf = sigm (s1[1] + a1[1] + b1g[1]);
      float gg = tanh_f(s1[2] + a1[2] + b1g[2]);
      float go = sigm (s1[3] + a1[3] + b1g[3]);
      c1 = gf*c1 + gi*gg;
      float h1v = go * tanh_f(c1);
      if(lane == 0)
        __hip_atomic_store(&h1buf[je], pack_vt(h1v, tt + 1u), __ATOMIC_RELAXED, __HIP_MEMORY_SCOPE_AGENT);
    }

    // shadow: RNG for this step + Whh0 rows (a0, used in P2's cell0)
    {
      const uint32_t kk0 = jax_word(2u*tt), kk1 = jax_word(2u*tt + 1u);
      const uint32_t bits = tf2x32(kk0, kk1, 0u, 0u).x;
      u = __uint_as_float((bits >> 9) | 0x3f800000u) - 1.0f;
    }
    float sa[4];
    #pragma unroll
    for(int r = 0; r < 4; r++) sa[r] = row_part(&w[4+r][0], lane, hv);
    #pragma unroll
    for(int off = 32; off > 0; off >>= 1){
      #pragma unroll
      for(int r = 0; r < 4; r++) sa[r] += __shfl_xor(sa[r], off, 64);
    }
    a0[0] = sa[0]; a0[1] = sa[1]; a0[2] = sa[2]; a0[3] = sa[3];

    // ================= P2: consume h1(t) =================
    poll_h(h1buf, tt + 1u, lane, hv);

    // critical: W2 row -> p,s -> cell0 -> publish h0(t+1)
    float z = row_part(&w[12][0], lane, hv);
    z = wred64(z) + b2v;
    const float p = sigm(z);
    const float s = (u < p) ? 1.f : 0.f;
    logp += s * __logf(p) + (1.f - s) * __logf(1.f - p);
    if(je == 0 && lane == 0) out[t] = s;
    {
      float gi = sigm (a0[0] + w0g[0]*s + b0g[0]);
      float gf = sigm (a0[1] + w0g[1]*s + b0g[1]);
      float gg = tanh_f(a0[2] + w0g[2]*s + b0g[2]);
      float go = sigm (a0[3] + w0g[3]*s + b0g[3]);
      c0 = gf*c0 + gi*gg;
      float h0v = go * tanh_f(c0);
      if(lane == 0)
        __hip_atomic_store(&h0buf[je], pack_vt(h0v, tt + 2u), __ATOMIC_RELAXED, __HIP_MEMORY_SCOPE_AGENT);
    }

    // shadow: Whh1 rows (a1 for next step's P1)
    float sb[4];
    #pragma unroll
    for(int r = 0; r < 4; r++) sb[r] = row_part(&w[8+r][0], lane, hv);
    #pragma unroll
    for(int off = 32; off > 0; off >>= 1){
      #pragma unroll
      for(int r = 0; r < 4; r++) sb[r] += __shfl_xor(sb[r], off, 64);
    }
    a1[0] = sb[0]; a1[1] = sb[1]; a1[2] = sb[2]; a1[3] = sb[3];
  }

  if(je == 0 && lane == 0) out[NSTEP] = logp;
}

extern "C" void kernel_launch(void* const* d_in, const int* in_sizes, int n_in,
                              void* d_out, int out_size, void* d_ws, size_t ws_size,
                              hipStream_t stream){
  unsigned long long* h0buf = (unsigned long long*)d_ws;   // 1024 slots
  unsigned long long* h1buf = h0buf + H;                   // 1024 slots
  hipLaunchKernelGGL(lstm_persist, dim3(NWG), dim3(BLK), 0, stream,
    (const float*)d_in[0],  (const float*)d_in[1],  (const float*)d_in[2],
    (const float*)d_in[3],  (const float*)d_in[4],  (const float*)d_in[5],  (const float*)d_in[6],
    (const float*)d_in[7],  (const float*)d_in[8],  (const float*)d_in[9],  (const float*)d_in[10],
    (const float*)d_in[11], (const float*)d_in[12],
    (float*)d_out, h0buf, h1buf);
}

// Round 3
// 33336.588 us; speedup vs baseline: 5.2284x; 5.2284x over previous
//
#include <hip/hip_runtime.h>
#include <stdint.h>
#include <math.h>

// Persistent barrier-free 2-layer LSTM rollout, MI355X (gfx950).
// 512 WGs x 64 thr (1 wave); wave w owns h-units {2w, 2w+1} of both layers.
// h exchanged as 512 8B slots {f16 val0 | f16 val1 | u32 step-tag} via
// relaxed agent-scope atomics. Per-slot stale re-poll (low LLC traffic).
// Critical chain/step: poll h0 -> 8 gate rows -> publish h1 ->
//                      poll h1 -> W2 row -> cell0 -> publish h0.
// Whh0/Whh1 rows + threefry RNG run post-publish (shadow time).

#define H     1024
#define NSTEP 8192
#define NWG   512
#define BLK   64
#define NROW  25   // 0-7 Wih1 (4 gates x 2 units), 8-15 Whh0, 16-23 Whh1, 24 W2

typedef _Float16 h2 __attribute__((ext_vector_type(2)));
typedef _Float16 h8 __attribute__((ext_vector_type(8)));

union U32H2 { uint32_t u; h2 v; };

__device__ __forceinline__ unsigned long long pack_vt(float v0, float v1, uint32_t tag){
  U32H2 p; p.v.x = (_Float16)v0; p.v.y = (_Float16)v1;
  return ((unsigned long long)tag << 32) | (unsigned long long)p.u;
}

// Exact JAX threefry2x32.
__device__ __forceinline__ uint2 tf2x32(uint32_t k0, uint32_t k1, uint32_t x0, uint32_t x1){
  uint32_t k2 = k0 ^ k1 ^ 0x1BD11BDAu;
  x0 += k0; x1 += k1;
#define TFR(r) { x0 += x1; x1 = (x1 << (r)) | (x1 >> (32 - (r))); x1 ^= x0; }
  TFR(13) TFR(15) TFR(26) TFR(6)
  x0 += k1; x1 += k2 + 1u;
  TFR(17) TFR(29) TFR(16) TFR(24)
  x0 += k2; x1 += k0 + 2u;
  TFR(13) TFR(15) TFR(26) TFR(6)
  x0 += k0; x1 += k1 + 3u;
  TFR(17) TFR(29) TFR(16) TFR(24)
  x0 += k1; x1 += k2 + 4u;
  TFR(13) TFR(15) TFR(26) TFR(6)
  x0 += k2; x1 += k0 + 5u;
#undef TFR
  uint2 r; r.x = x0; r.y = x1; return r;
}

// keys = threefry_split(key(42), 8192)
__device__ __forceinline__ uint32_t jax_word(uint32_t i){
  return (i < 8192u) ? tf2x32(0u, 42u, i, i + 8192u).x
                     : tf2x32(0u, 42u, i - 8192u, i).y;
}

__device__ __forceinline__ float wred64(float x){
  #pragma unroll
  for(int off = 32; off > 0; off >>= 1) x += __shfl_xor(x, off, 64);
  return x;
}

#if __has_builtin(__builtin_amdgcn_fdot2)
__device__ __forceinline__ float fdot2f(h2 a, h2 b, float c){ return __builtin_amdgcn_fdot2(a, b, c, false); }
#else
__device__ __forceinline__ float fdot2f(h2 a, h2 b, float c){
  return (float)a.x * (float)b.x + (float)a.y * (float)b.y + c;
}
#endif

__device__ __forceinline__ float sigm(float x){
  x = fminf(fmaxf(x, -30.f), 30.f);
  return 1.f / (1.f + __expf(-x));
}
__device__ __forceinline__ float tanh_f(float x){
  x = fminf(fmaxf(x, -15.f), 15.f);
  float e = __expf(2.f * x);
  return (e - 1.f) / (e + 1.f);
}

__device__ __forceinline__ unsigned long long ld_slot(const unsigned long long* p){
  return __hip_atomic_load((unsigned long long*)p, __ATOMIC_RELAXED, __HIP_MEMORY_SCOPE_AGENT);
}

// Poll this lane's 8 slots (fragment pairs [4l,4l+4) and [256+4l,+4)).
// Load all once, then spin ONLY on stale slots (minimal LLC traffic).
__device__ __forceinline__ void poll_h(const unsigned long long* __restrict__ buf,
                                       uint32_t tag, int lane, h2* hv){
  const unsigned long long* p0 = buf + (lane << 2);
  const unsigned long long* p1 = buf + 256 + (lane << 2);
  unsigned long long pv[8];
  #pragma unroll
  for(int k = 0; k < 4; k++) pv[k]     = ld_slot(p0 + k);
  #pragma unroll
  for(int k = 0; k < 4; k++) pv[4 + k] = ld_slot(p1 + k);
  #pragma unroll
  for(int k = 0; k < 8; k++){
    const unsigned long long* p = (k < 4) ? (p0 + k) : (p1 + (k - 4));
    while((uint32_t)(pv[k] >> 32) != tag){
      __builtin_amdgcn_s_sleep(1);
      pv[k] = ld_slot(p);
    }
  }
  #pragma unroll
  for(int k = 0; k < 8; k++){
    U32H2 u; u.u = (uint32_t)pv[k];
    hv[k] = u.v;
  }
}

// Row dot partial: lane l covers h2 [4l,4l+4) and [256+4l,+4): two b128
// LDS reads, lane stride 16B -> conflict-free.
__device__ __forceinline__ float row_part(const h2* __restrict__ wrow, int lane, const h2* hv){
  h8 wl = *(const h8*)(wrow + (lane << 2));
  h8 wh = *(const h8*)(wrow + 256 + (lane << 2));
  float a0 = 0.f, a1 = 0.f;
  h2 w;
  w = __builtin_shufflevector(wl, wl, 0, 1); a0 = fdot2f(w, hv[0], a0);
  w = __builtin_shufflevector(wl, wl, 2, 3); a1 = fdot2f(w, hv[1], a1);
  w = __builtin_shufflevector(wl, wl, 4, 5); a0 = fdot2f(w, hv[2], a0);
  w = __builtin_shufflevector(wl, wl, 6, 7); a1 = fdot2f(w, hv[3], a1);
  w = __builtin_shufflevector(wh, wh, 0, 1); a0 = fdot2f(w, hv[4], a0);
  w = __builtin_shufflevector(wh, wh, 2, 3); a1 = fdot2f(w, hv[5], a1);
  w = __builtin_shufflevector(wh, wh, 4, 5); a0 = fdot2f(w, hv[6], a0);
  w = __builtin_shufflevector(wh, wh, 6, 7); a1 = fdot2f(w, hv[7], a1);
  return a0 + a1;
}

__global__ void __launch_bounds__(BLK)
lstm_persist(const float* __restrict__ ctx,  const float* __restrict__ W1p,  const float* __restrict__ b1p,
             const float* __restrict__ Wih0, const float* __restrict__ Whh0,
             const float* __restrict__ bih0, const float* __restrict__ bhh0,
             const float* __restrict__ Wih1, const float* __restrict__ Whh1,
             const float* __restrict__ bih1, const float* __restrict__ bhh1,
             const float* __restrict__ W2p,  const float* __restrict__ b2p,
             float* __restrict__ out,
             unsigned long long* __restrict__ h0buf,
             unsigned long long* __restrict__ h1buf)
{
  __shared__ h2 w[NROW][H/2];   // 51.2 KB (<64KB/block cap); 2 WGs/CU

  const int lane = threadIdx.x;   // single wave per WG
  const int wg   = blockIdx.x;
  const int j0   = wg << 1;       // this wave's two h-units: j0, j0+1

  // ---- one-time: stage 25 rows as f16 (coalesced float4 reads)
  #pragma unroll 1
  for(int r = 0; r < NROW; r++){
    const float* rowp;
    if(r < 8)      { int g = r & 3,        j = j0 + (r >> 2);        rowp = Wih1 + (size_t)(g*H + j)*H; }
    else if(r < 16){ int rr = r - 8;  int g = rr & 3, j = j0 + (rr >> 2); rowp = Whh0 + (size_t)(g*H + j)*H; }
    else if(r < 24){ int rr = r - 16; int g = rr & 3, j = j0 + (rr >> 2); rowp = Whh1 + (size_t)(g*H + j)*H; }
    else           rowp = W2p;
    const float4* s4 = (const float4*)rowp;
    #pragma unroll
    for(int it = 0; it < 4; it++){
      float4 f = s4[lane + (it << 6)];
      h2 pa; pa.x = (_Float16)f.x; pa.y = (_Float16)f.y;
      h2 pb; pb.x = (_Float16)f.z; pb.y = (_Float16)f.w;
      const int ci = (lane + (it << 6)) << 1;
      w[r][ci] = pa; w[r][ci + 1] = pb;
    }
  }
  __syncthreads();

  // per-wave scalars for both units (uniform across lanes)
  float b0g[8], b1g[8], w0g[8];
  #pragma unroll
  for(int e = 0; e < 2; e++){
    const int j = j0 + e;
    #pragma unroll
    for(int g = 0; g < 4; g++){
      b0g[4*e + g] = bih0[g*H + j] + bhh0[g*H + j];
      b1g[4*e + g] = bih1[g*H + j] + bhh1[g*H + j];
      w0g[4*e + g] = Wih0[g*H + j];
    }
  }
  const float b2v = b2p[0];

  // x0 = W1 @ context + b1
  float xacc = 0.f;
  for(int c = lane; c < 512; c += 64) xacc += W1p[c] * ctx[c];
  const float x0 = wred64(xacc) + b1p[0];

  float c0[2], c1[2] = {0.f, 0.f}, logp = 0.f;
  float a0[8];
  float a1[8] = {0.f,0.f,0.f,0.f,0.f,0.f,0.f,0.f};

  // h0(0) from x0 for both units
  {
    float h0v[2];
    #pragma unroll
    for(int e = 0; e < 2; e++){
      float gi = sigm (w0g[4*e+0]*x0 + b0g[4*e+0]);
      float gf = sigm (w0g[4*e+1]*x0 + b0g[4*e+1]);
      float gg = tanh_f(w0g[4*e+2]*x0 + b0g[4*e+2]);
      float go = sigm (w0g[4*e+3]*x0 + b0g[4*e+3]);
      c0[e] = gi * gg;
      h0v[e] = go * tanh_f(c0[e]);
    }
    if(lane == 0)
      __hip_atomic_store(&h0buf[wg], pack_vt(h0v[0], h0v[1], 1u),
                         __ATOMIC_RELAXED, __HIP_MEMORY_SCOPE_AGENT);
  }

  h2 hv[8];
  float u = 0.f;

  #pragma unroll 1
  for(int t = 0; t < NSTEP; t++){
    const uint32_t tt = (uint32_t)t;

    // ================= P1: consume h0(t) =================
    poll_h(h0buf, tt + 1u, lane, hv);

    // critical: 8 layer-1 gate rows (Wih1, both units)
    float s1[8];
    #pragma unroll
    for(int r = 0; r < 8; r++) s1[r] = row_part(&w[r][0], lane, hv);
    #pragma unroll
    for(int off = 32; off > 0; off >>= 1){
      #pragma unroll
      for(int r = 0; r < 8; r++) s1[r] += __shfl_xor(s1[r], off, 64);
    }
    {
      float h1v[2];
      #pragma unroll
      for(int e = 0; e < 2; e++){
        float gi = sigm (s1[4*e+0] + a1[4*e+0] + b1g[4*e+0]);
        float gf = sigm (s1[4*e+1] + a1[4*e+1] + b1g[4*e+1]);
        float gg = tanh_f(s1[4*e+2] + a1[4*e+2] + b1g[4*e+2]);
        float go = sigm (s1[4*e+3] + a1[4*e+3] + b1g[4*e+3]);
        c1[e] = gf*c1[e] + gi*gg;
        h1v[e] = go * tanh_f(c1[e]);
      }
      if(lane == 0)
        __hip_atomic_store(&h1buf[wg], pack_vt(h1v[0], h1v[1], tt + 1u),
                           __ATOMIC_RELAXED, __HIP_MEMORY_SCOPE_AGENT);
    }

    // shadow: RNG + 8 Whh0 rows (a0 for P2's cell0)
    {
      const uint32_t kk0 = jax_word(2u*tt), kk1 = jax_word(2u*tt + 1u);
      const uint32_t bits = tf2x32(kk0, kk1, 0u, 0u).x;
      u = __uint_as_float((bits >> 9) | 0x3f800000u) - 1.0f;
    }
    float sa[8];
    #pragma unroll
    for(int r = 0; r < 8; r++) sa[r] = row_part(&w[8 + r][0], lane, hv);
    #pragma unroll
    for(int off = 32; off > 0; off >>= 1){
      #pragma unroll
      for(int r = 0; r < 8; r++) sa[r] += __shfl_xor(sa[r], off, 64);
    }
    #pragma unroll
    for(int r = 0; r < 8; r++) a0[r] = sa[r];

    // ================= P2: consume h1(t) =================
    poll_h(h1buf, tt + 1u, lane, hv);

    // critical: W2 row -> p,s -> cell0 -> publish h0(t+1)
    float z = row_part(&w[24][0], lane, hv);
    z = wred64(z) + b2v;
    const float p = sigm(z);
    const float s = (u < p) ? 1.f : 0.f;
    logp += s * __logf(p) + (1.f - s) * __logf(1.f - p);
    if(wg == 0 && lane == 0) out[t] = s;
    {
      float h0v[2];
      #pragma unroll
      for(int e = 0; e < 2; e++){
        float gi = sigm (a0[4*e+0] + w0g[4*e+0]*s + b0g[4*e+0]);
        float gf = sigm (a0[4*e+1] + w0g[4*e+1]*s + b0g[4*e+1]);
        float gg = tanh_f(a0[4*e+2] + w0g[4*e+2]*s + b0g[4*e+2]);
        float go = sigm (a0[4*e+3] + w0g[4*e+3]*s + b0g[4*e+3]);
        c0[e] = gf*c0[e] + gi*gg;
        h0v[e] = go * tanh_f(c0[e]);
      }
      if(lane == 0)
        __hip_atomic_store(&h0buf[wg], pack_vt(h0v[0], h0v[1], tt + 2u),
                           __ATOMIC_RELAXED, __HIP_MEMORY_SCOPE_AGENT);
    }

    // shadow: 8 Whh1 rows (a1 for next step's P1)
    float sb[8];
    #pragma unroll
    for(int r = 0; r < 8; r++) sb[r] = row_part(&w[16 + r][0], lane, hv);
    #pragma unroll
    for(int off = 32; off > 0; off >>= 1){
      #pragma unroll
      for(int r = 0; r < 8; r++) sb[r] += __shfl_xor(sb[r], off, 64);
    }
    #pragma unroll
    for(int r = 0; r < 8; r++) a1[r] = sb[r];
  }

  if(wg == 0 && lane == 0) out[NSTEP] = logp;
}

extern "C" void kernel_launch(void* const* d_in, const int* in_sizes, int n_in,
                              void* d_out, int out_size, void* d_ws, size_t ws_size,
                              hipStream_t stream){
  unsigned long long* h0buf = (unsigned long long*)d_ws;   // 512 slots
  unsigned long long* h1buf = h0buf + 512;                 // 512 slots
  hipLaunchKernelGGL(lstm_persist, dim3(NWG), dim3(BLK), 0, stream,
    (const float*)d_in[0],  (const float*)d_in[1],  (const float*)d_in[2],
    (const float*)d_in[3],  (const float*)d_in[4],  (const float*)d_in[5],  (const float*)d_in[6],
    (const float*)d_in[7],  (const float*)d_in[8],  (const float*)d_in[9],  (const float*)d_in[10],
    (const float*)d_in[11], (const float*)d_in[12],
    (float*)d_out, h0buf, h1buf);
}